// Round 16
// baseline (3178.270 us; speedup 1.0000x reference)
//
#include <hip/hip_runtime.h>
#include <hip/hip_fp16.h>

#define N_NODES   100000
#define N_EDGES   1600000
#define NUM_GRAPHS 64
#define EMBED     32
#define LAYERS    9
#define POOL_CHUNK 128
#define BUCKET_SHIFT 9   // 512 nodes per bucket (CSR build)
#define NB 196           // ceil(100000/512)
#define CAP 10240
#define CSR_CAP (CAP + 512)
#define FC_CHUNK 8192
#define FC_BLOCKS 196
#define DCLASS 64
#define DP_CHUNK 1024
#define DP_BLOCKS 98
// push-layer geometry
#define PB_SHIFT 7       // 128-node target buckets
#define PB_NODES 128
#define PBKT 782         // ceil(100000/128)
#define PCAP 2816        // edges+selfloops per push bucket (mean 2176, +14 sigma)
#define SRCBIN_SHIFT 10  // 1024-node source bins (32KB fp8 window)
#define NSRCBIN 98

typedef float floatx2 __attribute__((ext_vector_type(2)));

// ---------- bin edges into per-bucket fixed-capacity regions ----------
__global__ __launch_bounds__(256) void k_binfill(const int* __restrict__ ei,
                                                 int* __restrict__ bcursor,
                                                 int* __restrict__ binned) {
    __shared__ int hist[NB];
    __shared__ int rbase[NB];
    int tid = threadIdx.x;
    int e0 = blockIdx.x * FC_CHUNK;
    int e1 = min(e0 + FC_CHUNK, N_EDGES);
    for (int i = tid; i < NB; i += 256) hist[i] = 0;
    __syncthreads();
    for (int e = e0 + tid; e < e1; e += 256)
        atomicAdd(&hist[ei[N_EDGES + e] >> BUCKET_SHIFT], 1);
    __syncthreads();
    for (int i = tid; i < NB; i += 256) {
        int c = hist[i];
        rbase[i] = c ? atomicAdd(&bcursor[i], c) : 0;
    }
    __syncthreads();
    for (int i = tid; i < NB; i += 256) hist[i] = 0;
    __syncthreads();
    for (int e = e0 + tid; e < e1; e += 256) {
        int src = ei[e];
        int tgt = ei[N_EDGES + e];
        int b = tgt >> BUCKET_SHIFT;
        int r = atomicAdd(&hist[b], 1);
        binned[b * CAP + rbase[b] + r] = (src << BUCKET_SHIFT) | (tgt & 511);
    }
}

// ---------- per-bucket finalize: deg/offs/dinv + CSR fill ----------
__global__ __launch_bounds__(1024) void k_fill2(const int* __restrict__ binned,
        const int* __restrict__ bcursor,
        int* __restrict__ csr, int* __restrict__ offs, int* __restrict__ deg,
        float* __restrict__ dinv) {
    __shared__ int cnt[512];
    __shared__ int ps[256];
    __shared__ int lcur[512];
    int b = blockIdx.x, tid = threadIdx.x;
    int n0 = b << BUCKET_SHIFT;
    int nLoc = min(512, N_NODES - n0);
    int ebase = b * CAP;
    int ecnt  = bcursor[b];
    if (tid < 512) cnt[tid] = 0;
    __syncthreads();
    for (int i = tid; i < ecnt; i += 1024)
        atomicAdd(&cnt[binned[ebase + i] & 511], 1);
    __syncthreads();
    if (tid < 256) {
        int i0 = 2 * tid, i1 = 2 * tid + 1;
        int d0 = (i0 < nLoc) ? cnt[i0] + 1 : 0;
        int d1 = (i1 < nLoc) ? cnt[i1] + 1 : 0;
        int pair = d0 + d1;
        ps[tid] = pair;
        __syncthreads();
        for (int off = 1; off < 256; off <<= 1) {
            int t = (tid >= off) ? ps[tid - off] : 0;
            __syncthreads();
            ps[tid] += t;
            __syncthreads();
        }
        int excl = ps[tid] - pair;
        int gbase = b * CSR_CAP;
        if (i0 < nLoc) {
            int n = n0 + i0, o = gbase + excl;
            offs[n] = o; deg[n] = d0; dinv[n] = rsqrtf((float)d0);
            csr[o] = n; lcur[i0] = o + 1;   // self loop first
        }
        if (i1 < nLoc) {
            int n = n0 + i1, o = gbase + excl + d0;
            offs[n] = o; deg[n] = d1; dinv[n] = rsqrtf((float)d1);
            csr[o] = n; lcur[i1] = o + 1;
        }
    } else {
        __syncthreads();
        for (int off = 1; off < 256; off <<= 1) { __syncthreads(); __syncthreads(); }
    }
    __syncthreads();
    for (int i = tid; i < ecnt; i += 1024) {
        int v = binned[ebase + i];
        int pos = atomicAdd(&lcur[v & 511], 1);
        csr[pos] = v >> BUCKET_SHIFT;
    }
}

// ---------- degree counting-sort (for k_layer1 only) ----------
__global__ __launch_bounds__(256) void k_dhist(const int* __restrict__ deg,
                                               int* __restrict__ dtot) {
    __shared__ int hist[DCLASS];
    int tid = threadIdx.x;
    if (tid < DCLASS) hist[tid] = 0;
    __syncthreads();
    int n0 = blockIdx.x * DP_CHUNK;
    int n1 = min(n0 + DP_CHUNK, N_NODES);
    for (int n = n0 + tid; n < n1; n += 256)
        atomicAdd(&hist[min(deg[n], DCLASS - 1)], 1);
    __syncthreads();
    if (tid < DCLASS && hist[tid]) atomicAdd(&dtot[tid], hist[tid]);
}

__global__ void k_dscan(const int* __restrict__ dtot, int* __restrict__ dcur) {
    __shared__ int lds[DCLASS];
    int tid = threadIdx.x;
    int v = dtot[tid];
    lds[tid] = v;
    __syncthreads();
    for (int off = 1; off < DCLASS; off <<= 1) {
        int t = (tid >= off) ? lds[tid - off] : 0;
        __syncthreads();
        lds[tid] += t;
        __syncthreads();
    }
    dcur[tid] = lds[tid] - v;
}

__global__ __launch_bounds__(256) void k_dperm(const int* __restrict__ deg,
        int* __restrict__ dcur, int* __restrict__ perm) {
    __shared__ int hist[DCLASS];
    __shared__ int rbase[DCLASS];
    int tid = threadIdx.x;
    if (tid < DCLASS) hist[tid] = 0;
    __syncthreads();
    int n0 = blockIdx.x * DP_CHUNK;
    int n1 = min(n0 + DP_CHUNK, N_NODES);
    for (int n = n0 + tid; n < n1; n += 256)
        atomicAdd(&hist[min(deg[n], DCLASS - 1)], 1);
    __syncthreads();
    if (tid < DCLASS) {
        int c = hist[tid];
        rbase[tid] = c ? atomicAdd(&dcur[tid], c) : 0;
        hist[tid] = 0;
    }
    __syncthreads();
    for (int n = n0 + tid; n < n1; n += 256) {
        int cls = min(deg[n], DCLASS - 1);
        int r = atomicAdd(&hist[cls], 1);
        perm[rbase[cls] + r] = n;
    }
}

// ---------- push edge lists: per 128-node tgt bucket, sorted by source bin ----------
// payload: (src << 7) | tgt_local ; includes self loops (src == tgt)
__global__ __launch_bounds__(256) void k_pushsort(const int* __restrict__ csr,
        const int* __restrict__ offs, const int* __restrict__ deg,
        int* __restrict__ pedges, int* __restrict__ pecnt) {
    __shared__ int stage[PCAP];
    __shared__ int hist[NSRCBIN];
    __shared__ int cur[NSRCBIN];
    __shared__ int s_cnt;
    int p = blockIdx.x, tid = threadIdx.x;
    int n0 = p << PB_SHIFT;
    int nloc = min(PB_NODES, N_NODES - n0);
    for (int i = tid; i < NSRCBIN; i += 256) hist[i] = 0;
    if (tid == 0) s_cnt = 0;
    __syncthreads();
    if (tid < nloc) {
        int n = n0 + tid;
        int o = offs[n], d = deg[n];
        int base = atomicAdd(&s_cnt, d);
        for (int i = 0; i < d; ++i) {
            int src = csr[o + i];
            stage[base + i] = (src << PB_SHIFT) | tid;
            atomicAdd(&hist[src >> SRCBIN_SHIFT], 1);
        }
    }
    __syncthreads();
    int ecnt = s_cnt;
    if (tid == 0) {
        int run = 0;
        for (int i = 0; i < NSRCBIN; ++i) { cur[i] = run; run += hist[i]; }
        pecnt[p] = ecnt;
    }
    __syncthreads();
    int pbase = p * PCAP;
    for (int i = tid; i < ecnt; i += 256) {
        int v = stage[i];
        int bin = v >> (PB_SHIFT + SRCBIN_SHIFT);
        int pos = atomicAdd(&cur[bin], 1);
        pedges[pbase + pos] = v;
    }
}

// ---------- layer-1 tables ----------
__global__ void k_m1v1(const float* __restrict__ eW, const float* __restrict__ eb,
                       const float* __restrict__ W1, float* __restrict__ m1v1) {
    int c = threadIdx.x;
    if (c >= 32) return;
    float m0 = 0.f, m1 = 0.f, v = 0.f;
    for (int k = 0; k < 32; ++k) {
        float w = W1[k * 32 + c];
        m0 = fmaf(eW[k],      w, m0);
        m1 = fmaf(eW[32 + k], w, m1);
        v  = fmaf(eb[k],      w, v);
    }
    m1v1[c] = m0; m1v1[32 + c] = m1; m1v1[64 + c] = v;
}

__global__ void k_dxx(const float* __restrict__ x, const float* __restrict__ dinv,
                      float4* __restrict__ dxx) {
    int n = blockIdx.x * 256 + threadIdx.x;
    if (n >= N_NODES) return;
    float dv = dinv[n];
    float2 xv = ((const float2*)x)[n];
    dxx[n] = make_float4(dv * xv.x, dv * xv.y, dv, 0.f);
}

// ---------- fused layer 1 (pull, compressed tables) -> fp8 ----------
__global__ __launch_bounds__(256) void k_layer1(
        const float4* __restrict__ dxx, const int* __restrict__ csr,
        const int* __restrict__ offs, const int* __restrict__ deg,
        const float* __restrict__ dinv, const int* __restrict__ perm,
        const float* __restrict__ m1v1, const float* __restrict__ b1,
        unsigned* __restrict__ gout) {
    __shared__ float M0[32], M1s[32], V[32], Bs[32];
    int tid = threadIdx.x;
    if (tid < 32) { M0[tid] = m1v1[tid]; M1s[tid] = m1v1[32 + tid];
                    V[tid] = m1v1[64 + tid]; Bs[tid] = b1[tid]; }
    __syncthreads();
    int r = blockIdx.x * 256 + tid;
    if (r >= N_NODES) return;
    int n = perm[r];
    int p = offs[n], pend = p + deg[n];
    float tx = 0.f, ty = 0.f, tz = 0.f;
    int base = p;
    for (; base + 4 <= pend; base += 4) {
        int e0 = csr[base], e1 = csr[base + 1], e2 = csr[base + 2], e3 = csr[base + 3];
        float4 v0 = dxx[e0], v1 = dxx[e1], v2 = dxx[e2], v3 = dxx[e3];
        tx += v0.x + v1.x + v2.x + v3.x;
        ty += v0.y + v1.y + v2.y + v3.y;
        tz += v0.z + v1.z + v2.z + v3.z;
    }
    for (; base < pend; ++base) {
        float4 v = dxx[csr[base]];
        tx += v.x; ty += v.y; tz += v.z;
    }
    float dv = dinv[n];
#pragma unroll
    for (int qq = 0; qq < 4; ++qq) {
        float hv[8];
#pragma unroll
        for (int cc = 0; cc < 8; ++cc) {
            int c = qq * 8 + cc;
            float z = fmaf(dv, fmaf(tx, M0[c], fmaf(ty, M1s[c], tz * V[c])), Bs[c]);
            hv[cc] = fmaxf(z, 0.f) * dv;
        }
        unsigned w0 = __builtin_amdgcn_cvt_pk_fp8_f32(hv[0], hv[1], 0, false);
        w0 = __builtin_amdgcn_cvt_pk_fp8_f32(hv[2], hv[3], w0, true);
        unsigned w1 = __builtin_amdgcn_cvt_pk_fp8_f32(hv[4], hv[5], 0, false);
        w1 = __builtin_amdgcn_cvt_pk_fp8_f32(hv[6], hv[7], w1, true);
        *(uint2*)(gout + n * 8 + qq * 2) = make_uint2(w0, w1);
    }
}

// ---------- push GCN layer: LDS fp32 accumulate, source-sorted edges ----------
__global__ __launch_bounds__(256) void k_push(
        const unsigned* __restrict__ g, const int* __restrict__ pedges,
        const int* __restrict__ pecnt, const float* __restrict__ dinv,
        const float* __restrict__ W, const float* __restrict__ b,
        unsigned* __restrict__ gout, __half* __restrict__ hfin, int last) {
    __shared__ float accf[PB_NODES * 33];   // +1 pad word per node row
    __shared__ float4 Wl[256];
    int p = blockIdx.x, tid = threadIdx.x;
    Wl[tid] = ((const float4*)W)[tid];
    for (int i = tid; i < PB_NODES * 33; i += 256) accf[i] = 0.f;
    __syncthreads();
    int n0 = p << PB_SHIFT;
    int ecnt = pecnt[p];
    int pbase = p * PCAP;
    for (int base = 0; base < ecnt; base += 256) {
        int idx = base + tid;
        if (idx < ecnt) {
            int v = pedges[pbase + idx];
            int src = v >> PB_SHIFT;
            int tl = v & (PB_NODES - 1);
            uint4 u0 = *(const uint4*)(g + src * 8);
            uint4 u1 = *(const uint4*)(g + src * 8 + 4);
            float* a = &accf[tl * 33];
            floatx2 f;
            f = __builtin_amdgcn_cvt_pk_f32_fp8(u0.x, false); atomicAdd(a+0,  f[0]); atomicAdd(a+1,  f[1]);
            f = __builtin_amdgcn_cvt_pk_f32_fp8(u0.x, true);  atomicAdd(a+2,  f[0]); atomicAdd(a+3,  f[1]);
            f = __builtin_amdgcn_cvt_pk_f32_fp8(u0.y, false); atomicAdd(a+4,  f[0]); atomicAdd(a+5,  f[1]);
            f = __builtin_amdgcn_cvt_pk_f32_fp8(u0.y, true);  atomicAdd(a+6,  f[0]); atomicAdd(a+7,  f[1]);
            f = __builtin_amdgcn_cvt_pk_f32_fp8(u0.z, false); atomicAdd(a+8,  f[0]); atomicAdd(a+9,  f[1]);
            f = __builtin_amdgcn_cvt_pk_f32_fp8(u0.z, true);  atomicAdd(a+10, f[0]); atomicAdd(a+11, f[1]);
            f = __builtin_amdgcn_cvt_pk_f32_fp8(u0.w, false); atomicAdd(a+12, f[0]); atomicAdd(a+13, f[1]);
            f = __builtin_amdgcn_cvt_pk_f32_fp8(u0.w, true);  atomicAdd(a+14, f[0]); atomicAdd(a+15, f[1]);
            f = __builtin_amdgcn_cvt_pk_f32_fp8(u1.x, false); atomicAdd(a+16, f[0]); atomicAdd(a+17, f[1]);
            f = __builtin_amdgcn_cvt_pk_f32_fp8(u1.x, true);  atomicAdd(a+18, f[0]); atomicAdd(a+19, f[1]);
            f = __builtin_amdgcn_cvt_pk_f32_fp8(u1.y, false); atomicAdd(a+20, f[0]); atomicAdd(a+21, f[1]);
            f = __builtin_amdgcn_cvt_pk_f32_fp8(u1.y, true);  atomicAdd(a+22, f[0]); atomicAdd(a+23, f[1]);
            f = __builtin_amdgcn_cvt_pk_f32_fp8(u1.z, false); atomicAdd(a+24, f[0]); atomicAdd(a+25, f[1]);
            f = __builtin_amdgcn_cvt_pk_f32_fp8(u1.z, true);  atomicAdd(a+26, f[0]); atomicAdd(a+27, f[1]);
            f = __builtin_amdgcn_cvt_pk_f32_fp8(u1.w, false); atomicAdd(a+28, f[0]); atomicAdd(a+29, f[1]);
            f = __builtin_amdgcn_cvt_pk_f32_fp8(u1.w, true);  atomicAdd(a+30, f[0]); atomicAdd(a+31, f[1]);
        }
    }
    __syncthreads();
    // epilogue: thread pair per node; half owns 16 output channels
    int j = tid >> 1, half = tid & 1;
    int nloc = min(PB_NODES, N_NODES - n0);
    if (j < nloc) {
        int n = n0 + j;
        float o0=0,o1=0,o2=0,o3=0,o4=0,o5=0,o6=0,o7=0,
              o8=0,o9=0,o10=0,o11=0,o12=0,o13=0,o14=0,o15=0;
#pragma unroll
        for (int k = 0; k < 32; ++k) {
            float sk = accf[j * 33 + k];
            float4 w0 = Wl[k * 8 + half * 4 + 0];
            float4 w1 = Wl[k * 8 + half * 4 + 1];
            float4 w2 = Wl[k * 8 + half * 4 + 2];
            float4 w3 = Wl[k * 8 + half * 4 + 3];
            o0  = fmaf(sk, w0.x, o0);  o1  = fmaf(sk, w0.y, o1);
            o2  = fmaf(sk, w0.z, o2);  o3  = fmaf(sk, w0.w, o3);
            o4  = fmaf(sk, w1.x, o4);  o5  = fmaf(sk, w1.y, o5);
            o6  = fmaf(sk, w1.z, o6);  o7  = fmaf(sk, w1.w, o7);
            o8  = fmaf(sk, w2.x, o8);  o9  = fmaf(sk, w2.y, o9);
            o10 = fmaf(sk, w2.z, o10); o11 = fmaf(sk, w2.w, o11);
            o12 = fmaf(sk, w3.x, o12); o13 = fmaf(sk, w3.y, o13);
            o14 = fmaf(sk, w3.z, o14); o15 = fmaf(sk, w3.w, o15);
        }
        float dv = dinv[n];
        float sc = last ? 1.0f : dv;
        const float4 b0 = ((const float4*)b)[half * 4 + 0];
        const float4 b1 = ((const float4*)b)[half * 4 + 1];
        const float4 b2 = ((const float4*)b)[half * 4 + 2];
        const float4 b3 = ((const float4*)b)[half * 4 + 3];
        float h0  = fmaxf(fmaf(dv, o0,  b0.x), 0.f) * sc;
        float h1  = fmaxf(fmaf(dv, o1,  b0.y), 0.f) * sc;
        float h2  = fmaxf(fmaf(dv, o2,  b0.z), 0.f) * sc;
        float h3  = fmaxf(fmaf(dv, o3,  b0.w), 0.f) * sc;
        float h4  = fmaxf(fmaf(dv, o4,  b1.x), 0.f) * sc;
        float h5  = fmaxf(fmaf(dv, o5,  b1.y), 0.f) * sc;
        float h6  = fmaxf(fmaf(dv, o6,  b1.z), 0.f) * sc;
        float h7  = fmaxf(fmaf(dv, o7,  b1.w), 0.f) * sc;
        float h8  = fmaxf(fmaf(dv, o8,  b2.x), 0.f) * sc;
        float h9  = fmaxf(fmaf(dv, o9,  b2.y), 0.f) * sc;
        float h10 = fmaxf(fmaf(dv, o10, b2.z), 0.f) * sc;
        float h11 = fmaxf(fmaf(dv, o11, b2.w), 0.f) * sc;
        float h12 = fmaxf(fmaf(dv, o12, b3.x), 0.f) * sc;
        float h13 = fmaxf(fmaf(dv, o13, b3.y), 0.f) * sc;
        float h14 = fmaxf(fmaf(dv, o14, b3.z), 0.f) * sc;
        float h15 = fmaxf(fmaf(dv, o15, b3.w), 0.f) * sc;
        if (!last) {
            unsigned w0 = __builtin_amdgcn_cvt_pk_fp8_f32(h0, h1, 0, false);
            w0 = __builtin_amdgcn_cvt_pk_fp8_f32(h2, h3, w0, true);
            unsigned w1 = __builtin_amdgcn_cvt_pk_fp8_f32(h4, h5, 0, false);
            w1 = __builtin_amdgcn_cvt_pk_fp8_f32(h6, h7, w1, true);
            unsigned w2 = __builtin_amdgcn_cvt_pk_fp8_f32(h8, h9, 0, false);
            w2 = __builtin_amdgcn_cvt_pk_fp8_f32(h10, h11, w2, true);
            unsigned w3 = __builtin_amdgcn_cvt_pk_fp8_f32(h12, h13, 0, false);
            w3 = __builtin_amdgcn_cvt_pk_fp8_f32(h14, h15, w3, true);
            *(uint4*)(gout + n * 8 + half * 4) = make_uint4(w0, w1, w2, w3);
        } else {
            __half2 p0 = __float22half2_rn(make_float2(h0, h1));
            __half2 p1 = __float22half2_rn(make_float2(h2, h3));
            __half2 p2 = __float22half2_rn(make_float2(h4, h5));
            __half2 p3 = __float22half2_rn(make_float2(h6, h7));
            __half2 p4 = __float22half2_rn(make_float2(h8, h9));
            __half2 p5 = __float22half2_rn(make_float2(h10, h11));
            __half2 p6 = __float22half2_rn(make_float2(h12, h13));
            __half2 p7 = __float22half2_rn(make_float2(h14, h15));
            uint4 oa, ob;
            oa.x = *reinterpret_cast<unsigned*>(&p0);
            oa.y = *reinterpret_cast<unsigned*>(&p1);
            oa.z = *reinterpret_cast<unsigned*>(&p2);
            oa.w = *reinterpret_cast<unsigned*>(&p3);
            ob.x = *reinterpret_cast<unsigned*>(&p4);
            ob.y = *reinterpret_cast<unsigned*>(&p5);
            ob.z = *reinterpret_cast<unsigned*>(&p6);
            ob.w = *reinterpret_cast<unsigned*>(&p7);
            *(uint4*)(hfin + n * 32 + half * 16)     = oa;
            *(uint4*)(hfin + n * 32 + half * 16 + 8) = ob;
        }
    }
}

// ---------- global mean pool ----------
__global__ __launch_bounds__(256) void k_pool(
        const __half* __restrict__ h, const int* __restrict__ batch,
        float* __restrict__ pool, int* __restrict__ cnt) {
    int tid = threadIdx.x;
    int c = tid & 31;
    int s = tid >> 5;
    int start = blockIdx.x * POOL_CHUNK;
    int end   = min(start + POOL_CHUNK, N_NODES);
    float acc = 0.f;
    int   count = 0;
    int   gcur = -1;
    for (int n = start + s; n < end; n += 8) {
        int g = batch[n];
        if (g != gcur) {
            if (gcur >= 0) {
                atomicAdd(&pool[gcur * EMBED + c], acc);
                if (c == 0) atomicAdd(&cnt[gcur], count);
            }
            gcur = g; acc = 0.f; count = 0;
        }
        acc += __half2float(h[n * EMBED + c]);
        count++;
    }
    if (gcur >= 0) {
        atomicAdd(&pool[gcur * EMBED + c], acc);
        if (c == 0) atomicAdd(&cnt[gcur], count);
    }
}

// ---------- final fc ----------
__global__ void k_final(const float* __restrict__ pool, const int* __restrict__ cnt,
                        const float* __restrict__ fcW, const float* __restrict__ fcb,
                        float* __restrict__ out) {
    int t = threadIdx.x;
    if (t >= NUM_GRAPHS * 2) return;
    int g = t >> 1, j = t & 1;
    float inv = 1.0f / fmaxf((float)cnt[g], 1.0f);
    float acc = fcb[j];
#pragma unroll
    for (int c = 0; c < EMBED; ++c)
        acc = fmaf(pool[g * EMBED + c] * inv, fcW[c * 2 + j], acc);
    out[g * 2 + j] = acc;
}

extern "C" void kernel_launch(void* const* d_in, const int* in_sizes, int n_in,
                              void* d_out, int out_size, void* d_ws, size_t ws_size,
                              hipStream_t stream) {
    const float* x       = (const float*)d_in[0];
    const int*   ei      = (const int*)  d_in[1];
    const int*   batch   = (const int*)  d_in[2];
    const float* eW      = (const float*)d_in[3];
    const float* eb      = (const float*)d_in[4];
    const float* convW   = (const float*)d_in[5];
    const float* convB   = (const float*)d_in[6];
    const float* fcW     = (const float*)d_in[7];
    const float* fcb     = (const float*)d_in[8];
    float* out = (float*)d_out;

    char* ws = (char*)d_ws;
    size_t off = 0;
    auto alloc = [&](size_t bytes) -> void* {
        void* p = ws + off;
        off = (off + bytes + 255) & ~(size_t)255;
        return p;
    };
    int*   deg     = (int*)  alloc(N_NODES * 4);
    float* dinv    = (float*)alloc(N_NODES * 4);
    int*   offs    = (int*)  alloc(N_NODES * 4);
    int*   perm    = (int*)  alloc(N_NODES * 4);
    int*   zblk    = (int*)  alloc((NB + DCLASS + NUM_GRAPHS * EMBED + NUM_GRAPHS) * 4);
    int*   bcursor = zblk;
    int*   dtot    = zblk + NB;
    float* pool    = (float*)(zblk + NB + DCLASS);
    int*   cnt     = zblk + NB + DCLASS + NUM_GRAPHS * EMBED;
    int*   dcur    = (int*)  alloc(DCLASS * 4);
    int*   csr     = (int*)  alloc((size_t)NB * CSR_CAP * 4);
    int*   binned  = (int*)  alloc((size_t)NB * CAP * 4);
    int*   pedges  = (int*)  alloc((size_t)PBKT * PCAP * 4);
    int*   pecnt   = (int*)  alloc(PBKT * 4);
    float4* dxx    = (float4*)alloc((size_t)N_NODES * 16);
    float* m1v1    = (float*)alloc(96 * 4);
    unsigned* g0   = (unsigned*)alloc((size_t)N_NODES * 32);   // fp8 rows
    unsigned* g1   = (unsigned*)alloc((size_t)N_NODES * 32);
    __half* hfin   = (__half*)alloc((size_t)N_NODES * EMBED * 2);

    hipMemsetAsync(zblk, 0, (NB + DCLASS + NUM_GRAPHS * EMBED + NUM_GRAPHS) * 4, stream);

    // bucketed CSR build
    k_binfill<<<FC_BLOCKS, 256, 0, stream>>>(ei, bcursor, binned);
    k_fill2  <<<NB, 1024, 0, stream>>>(binned, bcursor, csr, offs, deg, dinv);

    // push edge lists (source-bin sorted, incl. self loops)
    k_pushsort<<<PBKT, 256, 0, stream>>>(csr, offs, deg, pedges, pecnt);

    // degree counting-sort -> perm (for layer1)
    k_dhist<<<DP_BLOCKS, 256, 0, stream>>>(deg, dtot);
    k_dscan<<<1, DCLASS, 0, stream>>>(dtot, dcur);
    k_dperm<<<DP_BLOCKS, 256, 0, stream>>>(deg, dcur, perm);

    // layer-1 tables + layer 1 -> fp8
    k_m1v1<<<1, 64, 0, stream>>>(eW, eb, convW, m1v1);
    k_dxx <<<(N_NODES + 255) / 256, 256, 0, stream>>>(x, dinv, dxx);
    k_layer1<<<(N_NODES + 255) / 256, 256, 0, stream>>>(
        dxx, csr, offs, deg, dinv, perm, m1v1, convB, g0);

    // layers 2..9: push with LDS accumulation
    unsigned* gin = g0;
    unsigned* gout = g1;
    for (int l = 1; l < LAYERS; ++l) {
        k_push<<<PBKT, 256, 0, stream>>>(
            gin, pedges, pecnt, dinv,
            convW + (size_t)l * EMBED * EMBED, convB + (size_t)l * EMBED,
            gout, hfin, (l == LAYERS - 1) ? 1 : 0);
        unsigned* t = gin; gin = gout; gout = t;
    }

    // pool + final
    k_pool <<<(N_NODES + POOL_CHUNK - 1) / POOL_CHUNK, 256, 0, stream>>>(hfin, batch, pool, cnt);
    k_final<<<1, 128, 0, stream>>>(pool, cnt, fcW, fcb, out);
}